// Round 6
// baseline (93.156 us; speedup 1.0000x reference)
//
#include <hip/hip_runtime.h>
#include <math.h>

// Problem constants
#define NB    64     // batch
#define L0    128    // input length
#define C0    16     // input channels
#define KW    5      // conv kernel size
#define NF    8      // filters per group
#define CH1   128
#define CH2   1024
#define CH3   8192
#define NCHUNK 8     // channel chunks: 2 state ch -> 16 y1 ch -> 128 y2 ch -> 1024 y3 ch
#define NS     4     // time slices of block-3 output
#define SLICE  29    // L3 / NS
#define TROWS  (SLICE + 4)    // y2 rows per slice    = 33
#define Y1R    (SLICE + 8)    // y1 rows per slice    = 37
#define STR    (SLICE + 12)   // state rows per slice = 41
#define NFH    4     // conv3 filters per thread (8 split across fh=0,1)
#define NBATCH 2     // batches per block (halved vs R5 -> 4 blocks/CU, 16 waves/CU)
#define NBG    (NB / NBATCH)  // 32 batch groups

__device__ __forceinline__ float2 fma2(float2 a, float s, float2 c) {
    return make_float2(fmaf(a.x, s, c.x), fmaf(a.y, s, c.y));
}
__device__ __forceinline__ float2 relu2(float2 a) {
    return make_float2(fmaxf(a.x, 0.f), fmaxf(a.y, 0.f));
}
__device__ __forceinline__ float2 splat2(float s) { return make_float2(s, s); }

// ---------------------------------------------------------------------------
// Fused conv1+conv2+conv3+dense, batch-blocked x2, batch-innermost LDS layout.
// Grid: (chunk=8, bgroup=32, slice=4) = 1024 blocks.
// Occupancy experiment vs R5: LDS/block 39.3 KB -> 4 blocks/CU = 4 waves/SIMD
// (R5 was 2), while __launch_bounds__(256,4)'s 128-VGPR cap still holds all
// ~75 live registers (R3's failure was the 64-VGPR cap spilling weights, not
// TLP itself). W is prefetched one iteration ahead; main loop does one
// ds_read_b64 per iter (2-way bank aliasing = free).
// blockIdx.x = chunk pins each 950 KB W-slice to one XCD's L2 (linear%8).
// ---------------------------------------------------------------------------
__global__ __launch_bounds__(256, 4) void actor_fused_kernel(
    const float* __restrict__ state,   // [64][128][16]
    const float* __restrict__ k1,      // [5][1][128]
    const float* __restrict__ b1,      // [128]
    const float* __restrict__ k2,      // [5][1][1024]
    const float* __restrict__ b2,      // [1024]
    const float* __restrict__ k3,      // [5][1][8192]
    const float* __restrict__ b3,      // [8192]
    const float* __restrict__ W,       // [950272][2]
    float* __restrict__ partials)      // [64][8][4][2]
{
    const int chunk = blockIdx.x;      // 0..7
    const int bg    = blockIdx.y;      // 0..31
    const int slice = blockIdx.z;      // 0..3
    const int t0    = slice * SLICE;
    const int tid   = threadIdx.x;     // 0..255
    const int c3loc = tid >> 1;        // 0..127
    const int fh    = tid & 1;         // 0..1
    const int c3    = chunk * 128 + c3loc;

    __shared__ float  s_state[NBATCH][STR][2];  // 656 B
    __shared__ float2 s_y1[Y1R][16];            // {x,y}=batch, 4.6 KB
    __shared__ float2 tile[TROWS][128];         // {x,y}=batch, 33 KB

    // ---- stage state: half-block bb = tid>>7 loads batch bg*2+bb ----
    {
        int bb = tid >> 7, lt = tid & 127;
        const float* sp = state + (size_t)(bg * NBATCH + bb) * L0 * C0
                        + (size_t)t0 * C0 + chunk * 2;
        for (int i = lt; i < STR * 2; i += 128) {
            int r = i >> 1, c = i & 1;
            s_state[bb][r][c] = sp[r * C0 + c];
        }
    }
    __syncthreads();

    // ---- conv1: write component bb of s_y1[r][jloc] ----
    {
        int bb = tid >> 7, lt = tid & 127;
        for (int i = lt; i < Y1R * 16; i += 128) {
            int r = i >> 4, jloc = i & 15;
            int j = chunk * 16 + jloc;
            int cloc = jloc >> 3;
            float acc = b1[j];
#pragma unroll
            for (int k = 0; k < KW; ++k)
                acc = fmaf(s_state[bb][r + k][cloc], k1[k * CH1 + j], acc);
            ((float*)&s_y1[r][jloc])[bb] = fmaxf(acc, 0.f);
        }
    }
    __syncthreads();

    // ---- conv2: column c = tid&127, row-half h = tid>>7, both batches ----
    {
        int c = tid & 127, h = tid >> 7;
        int m = chunk * 128 + c;
        int jloc = c >> 3;
        float kk[KW], b2v = b2[m];
#pragma unroll
        for (int k = 0; k < KW; ++k) kk[k] = k2[k * CH2 + m];
        int r0 = h ? 17 : 0, r1 = h ? TROWS : 17;
        float2 u0 = s_y1[r0 + 0][jloc];
        float2 u1 = s_y1[r0 + 1][jloc];
        float2 u2 = s_y1[r0 + 2][jloc];
        float2 u3 = s_y1[r0 + 3][jloc];
        for (int r = r0; r < r1; ++r) {
            float2 u4 = s_y1[r + 4][jloc];
            float2 acc = splat2(b2v);
            acc = fma2(u0, kk[0], acc);
            acc = fma2(u1, kk[1], acc);
            acc = fma2(u2, kk[2], acc);
            acc = fma2(u3, kk[3], acc);
            acc = fma2(u4, kk[4], acc);
            tile[r][c] = relu2(acc);
            u0 = u1; u1 = u2; u2 = u3; u3 = u4;
        }
    }

    // ---- conv3 weights + bias for this thread's 4 filters (registers) ----
    float kw[KW][NFH], bv[NFH];
#pragma unroll
    for (int k = 0; k < KW; ++k)
#pragma unroll
        for (int f = 0; f < NFH; ++f)
            kw[k][f] = k3[k * CH3 + c3 * NF + fh * NFH + f];
#pragma unroll
    for (int f = 0; f < NFH; ++f)
        bv[f] = b3[c3 * NF + fh * NFH + f];

    __syncthreads();   // tile ready

    // ---- main loop: conv3 + relu + dense, batch-pair float2 ----
    float2 axv = splat2(0.f), ayv = splat2(0.f);

    const float4* __restrict__ wp =
        (const float4*)W + (size_t)t0 * 4096 + (size_t)c3 * 4 + fh * 2;
    float4 cq0 = wp[0];          // W for iteration t (pipelined)
    float4 cq1 = wp[1];

    float2 tw0 = tile[0][c3loc];
    float2 tw1 = tile[1][c3loc];
    float2 tw2 = tile[2][c3loc];
    float2 tw3 = tile[3][c3loc];

    for (int t = 0; t < SLICE; ++t) {
        float2 tw4 = tile[t + 4][c3loc];            // one ds_read_b64
        const float4* wn = wp + (t < SLICE - 1 ? 4096 : 0);  // prefetch t+1
        float4 nq0 = wn[0];
        float4 nq1 = wn[1];

        float2 v[NFH];
#pragma unroll
        for (int f = 0; f < NFH; ++f) {
            float2 a = splat2(bv[f]);
            a = fma2(tw0, kw[0][f], a);
            a = fma2(tw1, kw[1][f], a);
            a = fma2(tw2, kw[2][f], a);
            a = fma2(tw3, kw[3][f], a);
            a = fma2(tw4, kw[4][f], a);
            v[f] = relu2(a);
        }

        axv = fma2(v[0], cq0.x, axv); ayv = fma2(v[0], cq0.y, ayv);
        axv = fma2(v[1], cq0.z, axv); ayv = fma2(v[1], cq0.w, ayv);
        axv = fma2(v[2], cq1.x, axv); ayv = fma2(v[2], cq1.y, ayv);
        axv = fma2(v[3], cq1.z, axv); ayv = fma2(v[3], cq1.w, ayv);

        wp = wn; cq0 = nq0; cq1 = nq1;
        tw0 = tw1; tw1 = tw2; tw2 = tw3; tw3 = tw4;
    }

    // ---- wave butterfly reduction (per batch component), cross-wave combine ----
#pragma unroll
    for (int d = 32; d >= 1; d >>= 1) {
        axv.x += __shfl_down(axv.x, d, 64); ayv.x += __shfl_down(ayv.x, d, 64);
        axv.y += __shfl_down(axv.y, d, 64); ayv.y += __shfl_down(ayv.y, d, 64);
    }
    __shared__ float red[4][NBATCH][2];
    int wave = tid >> 6, lane = tid & 63;
    if (lane == 0) {
        red[wave][0][0] = axv.x; red[wave][0][1] = ayv.x;
        red[wave][1][0] = axv.y; red[wave][1][1] = ayv.y;
    }
    __syncthreads();
    if (tid < NBATCH * 2) {
        int bb = tid >> 1, a = tid & 1;
        float s = (red[0][bb][a] + red[1][bb][a]) + (red[2][bb][a] + red[3][bb][a]);
        int b = bg * NBATCH + bb;
        partials[(((size_t)b * NCHUNK + chunk) * NS + slice) * 2 + a] = s;
    }
}

// ---------------------------------------------------------------------------
// Combine 32 partials per (b, a), add dense bias, tanh.
// ---------------------------------------------------------------------------
__global__ __launch_bounds__(128) void finish_kernel(
    const float* __restrict__ partials,  // [64][8][4][2]
    const float* __restrict__ bd,        // [2]
    float* __restrict__ out)             // [64][2]
{
    int i = threadIdx.x;                 // 0..127
    int b = i >> 1, a = i & 1;
    float s = bd[a];
#pragma unroll
    for (int p = 0; p < NCHUNK * NS; ++p)
        s += partials[((size_t)b * NCHUNK * NS + p) * 2 + a];
    out[b * 2 + a] = tanhf(s);
}

extern "C" void kernel_launch(void* const* d_in, const int* in_sizes, int n_in,
                              void* d_out, int out_size, void* d_ws, size_t ws_size,
                              hipStream_t stream) {
    const float* state = (const float*)d_in[0];
    const float* k1    = (const float*)d_in[1];
    const float* b1    = (const float*)d_in[2];
    const float* k2    = (const float*)d_in[3];
    const float* b2    = (const float*)d_in[4];
    const float* k3    = (const float*)d_in[5];
    const float* b3    = (const float*)d_in[6];
    const float* W     = (const float*)d_in[7];
    const float* bd    = (const float*)d_in[8];
    float* out = (float*)d_out;

    float* partials = (float*)d_ws;   // 64*8*4*2 fp32 = 16 KB

    dim3 grid(NCHUNK, NBG, NS);
    actor_fused_kernel<<<grid, 256, 0, stream>>>(
        state, k1, b1, k2, b2, k3, b3, W, partials);

    finish_kernel<<<1, 128, 0, stream>>>(partials, bd, out);
}